// Round 1
// baseline (1459.331 us; speedup 1.0000x reference)
//
#include <hip/hip_runtime.h>

#define N_NODES 30000
#define N_EDGES 480000
#define C_CH    32
#define T_STEPS 12
#define CT      (C_CH * T_STEPS)        /* 384 */
#define NCT     (N_NODES * CT)          /* 11,520,000 */

// ---------------- CSR build ----------------

__global__ void hist_kernel(const int* __restrict__ ei, int* __restrict__ cnt) {
    int e = blockIdx.x * blockDim.x + threadIdx.x;
    if (e < N_EDGES) atomicAdd(&cnt[ei[N_EDGES + e]], 1);   // dst row
}

__global__ void scan_kernel(const int* __restrict__ cnt,
                            int* __restrict__ offs, int* __restrict__ cur) {
    __shared__ int part[1024];
    int tid = threadIdx.x;
    const int chunk = (N_NODES + 1023) / 1024;   // 30
    int start = tid * chunk;
    int end   = min(start + chunk, N_NODES);
    int s = 0;
    for (int i = start; i < end; ++i) s += cnt[i];
    part[tid] = s;
    __syncthreads();
    for (int off = 1; off < 1024; off <<= 1) {
        int v = 0;
        if (tid >= off) v = part[tid - off];
        __syncthreads();
        part[tid] += v;
        __syncthreads();
    }
    int run = (tid == 0) ? 0 : part[tid - 1];
    for (int i = start; i < end; ++i) {
        offs[i] = run; cur[i] = run;
        run += cnt[i];
    }
    if (tid == 1023) offs[N_NODES] = part[1023];
}

__global__ void scatter_kernel(const int* __restrict__ ei, const float* __restrict__ ew,
                               int* __restrict__ cur,
                               int* __restrict__ bsrc, float* __restrict__ bw) {
    int e = blockIdx.x * blockDim.x + threadIdx.x;
    if (e >= N_EDGES) return;
    int d   = ei[N_EDGES + e];
    int pos = atomicAdd(&cur[d], 1);
    bsrc[pos] = ei[e];       // src row
    bw[pos]   = ew[e];
}

// ---------------- per-branch compute ----------------

// h[n][c][t] = sum_k x[n][k][t] * W[k][c]
__global__ void linear_kernel(const float* __restrict__ x, const float* __restrict__ W,
                              float* __restrict__ h) {
    __shared__ float xs[CT];
    __shared__ float Ws[C_CH * C_CH];
    int n = blockIdx.x, tid = threadIdx.x;
    for (int i = tid; i < C_CH * C_CH; i += CT) Ws[i] = W[i];
    xs[tid] = x[n * CT + tid];
    __syncthreads();
    int c = tid / T_STEPS, t = tid % T_STEPS;
    float acc = 0.f;
#pragma unroll
    for (int k = 0; k < C_CH; ++k)
        acc += Ws[k * C_CH + c] * xs[k * T_STEPS + t];
    h[n * CT + tid] = acc;
}

// out[n][c][t] (+)= sum_{edges into n} w * h[src][c][t]   (+ bias on first branch)
__global__ void accum_kernel(const float* __restrict__ h,
                             const int* __restrict__ offs,
                             const int* __restrict__ bsrc, const float* __restrict__ bw,
                             float* __restrict__ out, const float* __restrict__ bias,
                             int addFlag) {
    int n = blockIdx.x, tid = threadIdx.x;
    int beg = offs[n], end = offs[n + 1];
    float acc = 0.f;
    for (int j = beg; j < end; ++j) {
        int   s = bsrc[j];
        float w = bw[j];
        acc += w * h[s * CT + tid];
    }
    int oi = n * CT + tid;
    if (addFlag) out[oi] += acc;
    else         out[oi] = acc + bias[tid / T_STEPS];
}

// ---------------- launch ----------------

extern "C" void kernel_launch(void* const* d_in, const int* in_sizes, int n_in,
                              void* d_out, int out_size, void* d_ws, size_t ws_size,
                              hipStream_t stream) {
    const float* x    = (const float*)d_in[0];
    const float* bias = (const float*)d_in[13];
    const int*   ei[4] = { (const int*)d_in[1], (const int*)d_in[4],
                           (const int*)d_in[7], (const int*)d_in[10] };
    const float* ew[4] = { (const float*)d_in[2], (const float*)d_in[5],
                           (const float*)d_in[8], (const float*)d_in[11] };
    const float* W[4]  = { (const float*)d_in[3], (const float*)d_in[6],
                           (const float*)d_in[9], (const float*)d_in[12] };
    float* out = (float*)d_out;

    char* ws = (char*)d_ws;
    size_t OFF_H    = 0;                                   // NCT f32
    size_t OFF_CNT  = OFF_H    + (size_t)NCT * 4;          // 4*N int
    size_t OFF_OFFS = OFF_CNT  + (size_t)4 * N_NODES * 4;  // 4*(N+1) int
    size_t OFF_CUR  = OFF_OFFS + (size_t)4 * (N_NODES + 1) * 4; // 4*N int
    size_t OFF_BSRC = OFF_CUR  + (size_t)4 * N_NODES * 4;  // 4*E int
    size_t OFF_BW   = OFF_BSRC + (size_t)4 * N_EDGES * 4;  // 4*E f32

    float* h    = (float*)(ws + OFF_H);
    int*   cnt  = (int*)  (ws + OFF_CNT);
    int*   offs = (int*)  (ws + OFF_OFFS);
    int*   cur  = (int*)  (ws + OFF_CUR);
    int*   bsrc = (int*)  (ws + OFF_BSRC);
    float* bw   = (float*)(ws + OFF_BW);

    hipMemsetAsync(cnt, 0, (size_t)4 * N_NODES * 4, stream);

    const int EB = (N_EDGES + 255) / 256;   // 1875
    for (int b = 0; b < 4; ++b)
        hist_kernel<<<EB, 256, 0, stream>>>(ei[b], cnt + b * N_NODES);
    for (int b = 0; b < 4; ++b)
        scan_kernel<<<1, 1024, 0, stream>>>(cnt + b * N_NODES,
                                            offs + b * (N_NODES + 1),
                                            cur + b * N_NODES);
    for (int b = 0; b < 4; ++b)
        scatter_kernel<<<EB, 256, 0, stream>>>(ei[b], ew[b], cur + b * N_NODES,
                                               bsrc + (size_t)b * N_EDGES,
                                               bw + (size_t)b * N_EDGES);

    for (int b = 0; b < 4; ++b) {
        linear_kernel<<<N_NODES, CT, 0, stream>>>(x, W[b], h);
        accum_kernel<<<N_NODES, CT, 0, stream>>>(h, offs + b * (N_NODES + 1),
                                                 bsrc + (size_t)b * N_EDGES,
                                                 bw + (size_t)b * N_EDGES,
                                                 out, bias, b);
    }
}

// Round 2
// 974.203 us; speedup vs baseline: 1.4980x; 1.4980x over previous
//
#include <hip/hip_runtime.h>

#define NN 30000
#define NE 480000
#define CC 32
#define TT 12
#define CT 384            /* C*T */
#define GPB 4             /* nodes per block in fused kernel */

// ---------------- CSR build (merged across 4 branches) ----------------

__global__ void hist_kernel(const int* __restrict__ ei0, const int* __restrict__ ei1,
                            const int* __restrict__ ei2, const int* __restrict__ ei3,
                            int* __restrict__ cnt) {
    int e = blockIdx.x * blockDim.x + threadIdx.x;
    int b = blockIdx.y;
    if (e >= NE) return;
    const int* ei = (b == 0) ? ei0 : (b == 1) ? ei1 : (b == 2) ? ei2 : ei3;
    atomicAdd(&cnt[b * NN + ei[NE + e]], 1);   // dst row
}

__global__ void scan_kernel(const int* __restrict__ cnt,
                            int* __restrict__ offs, int* __restrict__ cur) {
    __shared__ int part[1024];
    const int TOT = 4 * NN;                 // 120000
    const int CHUNK = (TOT + 1023) / 1024;  // 118
    int tid = threadIdx.x;
    int start = tid * CHUNK;
    int end = min(start + CHUNK, TOT);
    int s = 0;
    for (int i = start; i < end; ++i) s += cnt[i];
    part[tid] = s;
    __syncthreads();
    for (int off = 1; off < 1024; off <<= 1) {
        int v = 0;
        if (tid >= off) v = part[tid - off];
        __syncthreads();
        part[tid] += v;
        __syncthreads();
    }
    int run = (tid == 0) ? 0 : part[tid - 1];
    for (int i = start; i < end; ++i) {
        offs[i] = run; cur[i] = run;
        run += cnt[i];
    }
    if (tid == 1023) offs[TOT] = part[1023];
}

__global__ void scatter_kernel(const int* __restrict__ ei0, const int* __restrict__ ei1,
                               const int* __restrict__ ei2, const int* __restrict__ ei3,
                               const float* __restrict__ ew0, const float* __restrict__ ew1,
                               const float* __restrict__ ew2, const float* __restrict__ ew3,
                               int* __restrict__ cur, int2* __restrict__ pairs) {
    int e = blockIdx.x * blockDim.x + threadIdx.x;
    int b = blockIdx.y;
    if (e >= NE) return;
    const int*   ei = (b == 0) ? ei0 : (b == 1) ? ei1 : (b == 2) ? ei2 : ei3;
    const float* ew = (b == 0) ? ew0 : (b == 1) ? ew1 : (b == 2) ? ew2 : ew3;
    int d = ei[NE + e];
    int pos = atomicAdd(&cur[b * NN + d], 1);
    int2 p; p.x = ei[e]; p.y = __float_as_int(ew[e]);
    pairs[pos] = p;
}

// ---------------- fused gather (raw x) + per-node 32x32 matmul ----------------
// agg_b[n][k][t] = sum_{edges into n, branch b} w * x[src][k][t]
// out[n][c][t]   = bias[c] + sum_b sum_k agg_b[n][k][t] * W_b[k][c]

__global__ __launch_bounds__(384, 8)
void fused_kernel(const float* __restrict__ x, const int2* __restrict__ pairs,
                  const int* __restrict__ offs,
                  const float* __restrict__ W0, const float* __restrict__ W1,
                  const float* __restrict__ W2, const float* __restrict__ W3,
                  const float* __restrict__ bias, float* __restrict__ out) {
    __shared__ float aggL[GPB * 4 * CT];      // 4 nodes x 4 branches x 384 = 24 KB
    const int tid = threadIdx.x;
    const int n0 = blockIdx.x * GPB;

    // ---- gather phase: thread tid owns element tid of each node's row ----
    for (int g = 0; g < GPB; ++g) {
        int n = n0 + g;
        for (int b = 0; b < 4; ++b) {
            int beg = offs[b * NN + n];
            int end = offs[b * NN + n + 1];
            float acc0 = 0.f, acc1 = 0.f;
            int j = beg;
            for (; j + 4 <= end; j += 4) {
                int2 p0 = pairs[j];
                int2 p1 = pairs[j + 1];
                int2 p2 = pairs[j + 2];
                int2 p3 = pairs[j + 3];
                float l0 = x[p0.x * CT + tid];
                float l1 = x[p1.x * CT + tid];
                float l2 = x[p2.x * CT + tid];
                float l3 = x[p3.x * CT + tid];
                acc0 = fmaf(__int_as_float(p0.y), l0, acc0);
                acc1 = fmaf(__int_as_float(p1.y), l1, acc1);
                acc0 = fmaf(__int_as_float(p2.y), l2, acc0);
                acc1 = fmaf(__int_as_float(p3.y), l3, acc1);
            }
            for (; j < end; ++j) {
                int2 p = pairs[j];
                acc0 = fmaf(__int_as_float(p.y), x[p.x * CT + tid], acc0);
            }
            aggL[(g * 4 + b) * CT + tid] = acc0 + acc1;
        }
    }
    __syncthreads();

    // ---- matmul phase: thread -> (g, q, t), computes c = q*4 .. q*4+3 ----
    const int g = tid / 96;
    const int rem = tid % 96;
    const int q = rem / TT;        // 0..7
    const int t = rem % TT;        // 0..11
    float acc[4];
#pragma unroll
    for (int i = 0; i < 4; ++i) acc[i] = bias[q * 4 + i];

    const float* Ws[4] = { W0, W1, W2, W3 };
#pragma unroll
    for (int b = 0; b < 4; ++b) {
        const float* __restrict__ Wb = Ws[b];
        const float* __restrict__ aL = &aggL[(g * 4 + b) * CT];
        // k in two halves of 16 to bound register pressure
#pragma unroll
        for (int h = 0; h < 2; ++h) {
            float row[16];
#pragma unroll
            for (int k = 0; k < 16; ++k) row[k] = aL[(h * 16 + k) * TT + t];
#pragma unroll
            for (int k = 0; k < 16; ++k) {
#pragma unroll
                for (int i = 0; i < 4; ++i)
                    acc[i] = fmaf(row[k], Wb[(h * 16 + k) * CC + q * 4 + i], acc[i]);
            }
        }
    }

#pragma unroll
    for (int i = 0; i < 4; ++i)
        out[(n0 + g) * CT + (q * 4 + i) * TT + t] = acc[i];
}

// ---------------- launch ----------------

extern "C" void kernel_launch(void* const* d_in, const int* in_sizes, int n_in,
                              void* d_out, int out_size, void* d_ws, size_t ws_size,
                              hipStream_t stream) {
    const float* x    = (const float*)d_in[0];
    const float* bias = (const float*)d_in[13];
    const int*   ei[4] = { (const int*)d_in[1], (const int*)d_in[4],
                           (const int*)d_in[7], (const int*)d_in[10] };
    const float* ew[4] = { (const float*)d_in[2], (const float*)d_in[5],
                           (const float*)d_in[8], (const float*)d_in[11] };
    const float* W[4]  = { (const float*)d_in[3], (const float*)d_in[6],
                           (const float*)d_in[9], (const float*)d_in[12] };
    float* out = (float*)d_out;

    char* ws = (char*)d_ws;
    size_t OFF_PAIRS = 0;                                    // 4E int2 = 15.36 MB
    size_t OFF_CNT   = OFF_PAIRS + (size_t)4 * NE * 8;       // 4N int
    size_t OFF_OFFS  = OFF_CNT   + (size_t)4 * NN * 4;       // 4N+1 int
    size_t OFF_CUR   = OFF_OFFS  + (size_t)(4 * NN + 1) * 4; // 4N int

    int2* pairs = (int2*)(ws + OFF_PAIRS);
    int*  cnt   = (int*) (ws + OFF_CNT);
    int*  offs  = (int*) (ws + OFF_OFFS);
    int*  cur   = (int*) (ws + OFF_CUR);

    hipMemsetAsync(cnt, 0, (size_t)4 * NN * 4, stream);

    dim3 eg((NE + 255) / 256, 4);
    hist_kernel<<<eg, 256, 0, stream>>>(ei[0], ei[1], ei[2], ei[3], cnt);
    scan_kernel<<<1, 1024, 0, stream>>>(cnt, offs, cur);
    scatter_kernel<<<eg, 256, 0, stream>>>(ei[0], ei[1], ei[2], ei[3],
                                           ew[0], ew[1], ew[2], ew[3],
                                           cur, pairs);

    fused_kernel<<<NN / GPB, 384, 0, stream>>>(x, pairs, offs,
                                               W[0], W[1], W[2], W[3],
                                               bias, out);
}

// Round 3
// 921.734 us; speedup vs baseline: 1.5832x; 1.0569x over previous
//
#include <hip/hip_runtime.h>
#include <hip/hip_fp16.h>

#define NN 30000
#define NE 480000
#define CC 32
#define TT 12
#define CT 384            /* C*T */
#define CT2 192           /* CT/2 half2 words per row */
#define GPB 4             /* nodes per block in fused kernel */

// ---------------- x -> fp16 conversion ----------------

__global__ void conv_kernel(const float2* __restrict__ x2, __half2* __restrict__ xh) {
    int i = blockIdx.x * blockDim.x + threadIdx.x;
    if (i < NN * CT2) {
        float2 v = x2[i];
        xh[i] = __floats2half2_rn(v.x, v.y);
    }
}

// ---------------- CSR build (merged across 4 branches) ----------------

__global__ void hist_kernel(const int* __restrict__ ei0, const int* __restrict__ ei1,
                            const int* __restrict__ ei2, const int* __restrict__ ei3,
                            int* __restrict__ cnt) {
    int e = blockIdx.x * blockDim.x + threadIdx.x;
    int b = blockIdx.y;
    if (e >= NE) return;
    const int* ei = (b == 0) ? ei0 : (b == 1) ? ei1 : (b == 2) ? ei2 : ei3;
    atomicAdd(&cnt[b * NN + ei[NE + e]], 1);   // dst row
}

__global__ void scan_kernel(const int* __restrict__ cnt,
                            int* __restrict__ offs, int* __restrict__ cur) {
    __shared__ int part[1024];
    const int TOT = 4 * NN;                 // 120000
    const int CHUNK = (TOT + 1023) / 1024;  // 118
    int tid = threadIdx.x;
    int start = tid * CHUNK;
    int end = min(start + CHUNK, TOT);
    int s = 0;
    for (int i = start; i < end; ++i) s += cnt[i];
    part[tid] = s;
    __syncthreads();
    for (int off = 1; off < 1024; off <<= 1) {
        int v = 0;
        if (tid >= off) v = part[tid - off];
        __syncthreads();
        part[tid] += v;
        __syncthreads();
    }
    int run = (tid == 0) ? 0 : part[tid - 1];
    for (int i = start; i < end; ++i) {
        offs[i] = run; cur[i] = run;
        run += cnt[i];
    }
    if (tid == 1023) offs[TOT] = part[1023];
}

__global__ void scatter_kernel(const int* __restrict__ ei0, const int* __restrict__ ei1,
                               const int* __restrict__ ei2, const int* __restrict__ ei3,
                               const float* __restrict__ ew0, const float* __restrict__ ew1,
                               const float* __restrict__ ew2, const float* __restrict__ ew3,
                               int* __restrict__ cur, int2* __restrict__ pairs) {
    int e = blockIdx.x * blockDim.x + threadIdx.x;
    int b = blockIdx.y;
    if (e >= NE) return;
    const int*   ei = (b == 0) ? ei0 : (b == 1) ? ei1 : (b == 2) ? ei2 : ei3;
    const float* ew = (b == 0) ? ew0 : (b == 1) ? ew1 : (b == 2) ? ew2 : ew3;
    int d = ei[NE + e];
    int pos = atomicAdd(&cur[b * NN + d], 1);
    int2 p; p.x = ei[e]; p.y = __float_as_int(ew[e]);
    pairs[pos] = p;
}

// ---------------- fused gather (fp16 x) + per-node 32x32 matmul ----------------
// agg_b[n][k][t] = sum_{edges into n, branch b} w * x[src][k][t]
// out[n][c][t]   = bias[c] + sum_b sum_k agg_b[n][k][t] * W_b[k][c]

__global__ __launch_bounds__(384, 8)
void fused_kernel(const __half2* __restrict__ xh, const int2* __restrict__ pairs,
                  const int* __restrict__ offs,
                  const float* __restrict__ W0, const float* __restrict__ W1,
                  const float* __restrict__ W2, const float* __restrict__ W3,
                  const float* __restrict__ bias, float* __restrict__ out) {
    __shared__ float aggL[GPB * 4 * CT];      // 4 nodes x 4 branches x 384 = 24 KB
    const int tid = threadIdx.x;
    const int n0 = blockIdx.x * GPB;

    // ---- gather phase: 2 wave-aligned groups of 192 lanes; lane u owns half2 u ----
    const int grp = tid / CT2;                // waves 0-2 -> 0, waves 3-5 -> 1
    const int u   = tid % CT2;

    for (int p = grp; p < GPB * 4; p += 2) {
        const int g = p >> 2, b = p & 3;
        const int row = b * NN + n0 + g;
        const int beg = offs[row];
        const int end = offs[row + 1];
        float ax0 = 0.f, ay0 = 0.f, ax1 = 0.f, ay1 = 0.f;
        int j = beg;
        for (; j + 4 <= end; j += 4) {
            int2 p0 = pairs[j];
            int2 p1 = pairs[j + 1];
            int2 p2 = pairs[j + 2];
            int2 p3 = pairs[j + 3];
            __half2 h0 = xh[p0.x * CT2 + u];
            __half2 h1 = xh[p1.x * CT2 + u];
            __half2 h2 = xh[p2.x * CT2 + u];
            __half2 h3 = xh[p3.x * CT2 + u];
            float w0 = __int_as_float(p0.y), w1 = __int_as_float(p1.y);
            float w2 = __int_as_float(p2.y), w3 = __int_as_float(p3.y);
            float2 f0 = __half22float2(h0);
            float2 f1 = __half22float2(h1);
            float2 f2 = __half22float2(h2);
            float2 f3 = __half22float2(h3);
            ax0 = fmaf(w0, f0.x, ax0); ay0 = fmaf(w0, f0.y, ay0);
            ax1 = fmaf(w1, f1.x, ax1); ay1 = fmaf(w1, f1.y, ay1);
            ax0 = fmaf(w2, f2.x, ax0); ay0 = fmaf(w2, f2.y, ay0);
            ax1 = fmaf(w3, f3.x, ax1); ay1 = fmaf(w3, f3.y, ay1);
        }
        for (; j < end; ++j) {
            int2 pp = pairs[j];
            float w = __int_as_float(pp.y);
            float2 f = __half22float2(xh[pp.x * CT2 + u]);
            ax0 = fmaf(w, f.x, ax0); ay0 = fmaf(w, f.y, ay0);
        }
        aggL[(g * 4 + b) * CT + 2 * u]     = ax0 + ax1;
        aggL[(g * 4 + b) * CT + 2 * u + 1] = ay0 + ay1;
    }
    __syncthreads();

    // ---- matmul phase: thread -> (g, q, t), computes c = q*4 .. q*4+3 ----
    const int g = tid / 96;
    const int rem = tid % 96;
    const int q = rem / TT;        // 0..7
    const int t = rem % TT;        // 0..11
    float acc[4];
#pragma unroll
    for (int i = 0; i < 4; ++i) acc[i] = bias[q * 4 + i];

    const float* Ws[4] = { W0, W1, W2, W3 };
#pragma unroll
    for (int b = 0; b < 4; ++b) {
        const float* __restrict__ Wb = Ws[b];
        const float* __restrict__ aL = &aggL[(g * 4 + b) * CT];
#pragma unroll
        for (int h = 0; h < 2; ++h) {
            float row[16];
#pragma unroll
            for (int k = 0; k < 16; ++k) row[k] = aL[(h * 16 + k) * TT + t];
#pragma unroll
            for (int k = 0; k < 16; ++k) {
#pragma unroll
                for (int i = 0; i < 4; ++i)
                    acc[i] = fmaf(row[k], Wb[(h * 16 + k) * CC + q * 4 + i], acc[i]);
            }
        }
    }

#pragma unroll
    for (int i = 0; i < 4; ++i)
        out[(n0 + g) * CT + (q * 4 + i) * TT + t] = acc[i];
}

// ---------------- launch ----------------

extern "C" void kernel_launch(void* const* d_in, const int* in_sizes, int n_in,
                              void* d_out, int out_size, void* d_ws, size_t ws_size,
                              hipStream_t stream) {
    const float* x    = (const float*)d_in[0];
    const float* bias = (const float*)d_in[13];
    const int*   ei[4] = { (const int*)d_in[1], (const int*)d_in[4],
                           (const int*)d_in[7], (const int*)d_in[10] };
    const float* ew[4] = { (const float*)d_in[2], (const float*)d_in[5],
                           (const float*)d_in[8], (const float*)d_in[11] };
    const float* W[4]  = { (const float*)d_in[3], (const float*)d_in[6],
                           (const float*)d_in[9], (const float*)d_in[12] };
    float* out = (float*)d_out;

    char* ws = (char*)d_ws;
    size_t OFF_PAIRS = 0;                                    // 4E int2 = 15.36 MB
    size_t OFF_XH    = OFF_PAIRS + (size_t)4 * NE * 8;       // N*CT2 half2 = 23 MB
    size_t OFF_CNT   = OFF_XH    + (size_t)NN * CT2 * 4;     // 4N int
    size_t OFF_OFFS  = OFF_CNT   + (size_t)4 * NN * 4;       // 4N+1 int
    size_t OFF_CUR   = OFF_OFFS  + (size_t)(4 * NN + 1) * 4; // 4N int

    int2*    pairs = (int2*)   (ws + OFF_PAIRS);
    __half2* xh    = (__half2*)(ws + OFF_XH);
    int*     cnt   = (int*)    (ws + OFF_CNT);
    int*     offs  = (int*)    (ws + OFF_OFFS);
    int*     cur   = (int*)    (ws + OFF_CUR);

    hipMemsetAsync(cnt, 0, (size_t)4 * NN * 4, stream);

    conv_kernel<<<(NN * CT2 + 255) / 256, 256, 0, stream>>>((const float2*)x, xh);

    dim3 eg((NE + 255) / 256, 4);
    hist_kernel<<<eg, 256, 0, stream>>>(ei[0], ei[1], ei[2], ei[3], cnt);
    scan_kernel<<<1, 1024, 0, stream>>>(cnt, offs, cur);
    scatter_kernel<<<eg, 256, 0, stream>>>(ei[0], ei[1], ei[2], ei[3],
                                           ew[0], ew[1], ew[2], ew[3],
                                           cur, pairs);

    fused_kernel<<<NN / GPB, 384, 0, stream>>>(xh, pairs, offs,
                                               W[0], W[1], W[2], W[3],
                                               bias, out);
}

// Round 4
// 490.376 us; speedup vs baseline: 2.9759x; 1.8796x over previous
//
#include <hip/hip_runtime.h>
#include <hip/hip_fp16.h>

#define NN 30000
#define NE 480000
#define CC 32
#define TT 12
#define CT 384            /* C*T */
#define CT2 192           /* CT/2 half2 words per row */
#define GPB 6             /* nodes per block in fused kernel */
#define NTASK (GPB * 4)   /* 24 */
#define TOT (4 * NN)      /* 120000 */
#define NB  118           /* ceil(TOT/1024) */

// ---------------- x -> fp16 conversion ----------------

__global__ void conv_kernel(const float2* __restrict__ x2, __half2* __restrict__ xh) {
    int i = blockIdx.x * blockDim.x + threadIdx.x;
    if (i < NN * CT2) {
        float2 v = x2[i];
        xh[i] = __floats2half2_rn(v.x, v.y);
    }
}

// ---------------- CSR build ----------------

__global__ void hist_kernel(const int* __restrict__ ei0, const int* __restrict__ ei1,
                            const int* __restrict__ ei2, const int* __restrict__ ei3,
                            int* __restrict__ cnt) {
    int e = blockIdx.x * blockDim.x + threadIdx.x;
    int b = blockIdx.y;
    if (e >= NE) return;
    const int* ei = (b == 0) ? ei0 : (b == 1) ? ei1 : (b == 2) ? ei2 : ei3;
    atomicAdd(&cnt[b * NN + ei[NE + e]], 1);   // dst row
}

// coalesced 3-phase scan over TOT elements
__global__ void scanA_kernel(const int* __restrict__ cnt,
                             int* __restrict__ pre, int* __restrict__ bsum) {
    __shared__ int s[1024];
    int tid = threadIdx.x;
    int i = blockIdx.x * 1024 + tid;
    int v = (i < TOT) ? cnt[i] : 0;
    s[tid] = v;
    __syncthreads();
    for (int off = 1; off < 1024; off <<= 1) {
        int t = (tid >= off) ? s[tid - off] : 0;
        __syncthreads();
        s[tid] += t;
        __syncthreads();
    }
    if (i < TOT) pre[i] = s[tid] - v;          // exclusive in-block
    if (tid == 1023) bsum[blockIdx.x] = s[1023];
}

__global__ void scanB_kernel(const int* __restrict__ bsum,
                             int* __restrict__ bbase, int* __restrict__ offs) {
    __shared__ int s[128];
    int tid = threadIdx.x;
    int v = (tid < NB) ? bsum[tid] : 0;
    s[tid] = v;
    __syncthreads();
    for (int off = 1; off < 128; off <<= 1) {
        int t = (tid >= off) ? s[tid - off] : 0;
        __syncthreads();
        s[tid] += t;
        __syncthreads();
    }
    if (tid < NB) bbase[tid] = s[tid] - v;
    if (tid == 127) offs[TOT] = s[127];
}

__global__ void scanC_kernel(const int* __restrict__ pre, const int* __restrict__ bbase,
                             int* __restrict__ offs, int* __restrict__ cur) {
    int i = blockIdx.x * 1024 + threadIdx.x;
    if (i < TOT) {
        int o = bbase[blockIdx.x] + pre[i];
        offs[i] = o;
        cur[i] = o;
    }
}

// pack edge as u32: src in [0:16), fp16 weight in [16:32)
__global__ void scatter_kernel(const int* __restrict__ ei0, const int* __restrict__ ei1,
                               const int* __restrict__ ei2, const int* __restrict__ ei3,
                               const float* __restrict__ ew0, const float* __restrict__ ew1,
                               const float* __restrict__ ew2, const float* __restrict__ ew3,
                               int* __restrict__ cur, unsigned int* __restrict__ pairs) {
    int e = blockIdx.x * blockDim.x + threadIdx.x;
    int b = blockIdx.y;
    if (e >= NE) return;
    const int*   ei = (b == 0) ? ei0 : (b == 1) ? ei1 : (b == 2) ? ei2 : ei3;
    const float* ew = (b == 0) ? ew0 : (b == 1) ? ew1 : (b == 2) ? ew2 : ew3;
    int d = ei[NE + e];
    int pos = atomicAdd(&cur[b * NN + d], 1);
    unsigned int w16 = (unsigned int)__half_as_ushort(__float2half_rn(ew[e]));
    pairs[pos] = (unsigned int)ei[e] | (w16 << 16);
}

// ---------------- fused gather (fp16 x, wave-per-node) + per-node matmul ----------------

__global__ __launch_bounds__(384, 6)
void fused_kernel(const char* __restrict__ xh,      // fp16 x rows, 768 B stride
                  const unsigned int* __restrict__ pairs,
                  const int* __restrict__ offs,
                  const float* __restrict__ W0, const float* __restrict__ W1,
                  const float* __restrict__ W2, const float* __restrict__ W3,
                  const float* __restrict__ bias, float* __restrict__ out) {
    __shared__ float aggL[NTASK * CT];     // 24 x 384 x 4 = 36 KB
    const int tid  = threadIdx.x;
    const int wave = tid >> 6;             // 0..5 -> node g = wave
    const int lane = tid & 63;
    const int n0 = blockIdx.x * GPB;

    // ---- fetch (beg,end) for this wave's 4 tasks via 8 lanes + shuffle ----
    int v = 0;
    if (lane < 8) {
        int p = 4 * wave + (lane >> 1);            // task id
        int row = (p & 3) * NN + n0 + (p >> 2) + (lane & 1);
        v = offs[row];
    }
    int beg[4], cnt[4];
#pragma unroll
    for (int k = 0; k < 4; ++k) {
        int b = __shfl(v, 2 * k, 64);
        int e = __shfl(v, 2 * k + 1, 64);
        beg[k] = b; cnt[k] = e - b;
    }
    // ---- preload pair words (first 64 edges of each task) ----
    unsigned int pb[4];
#pragma unroll
    for (int k = 0; k < 4; ++k) {
        pb[k] = 0;
        if (lane < cnt[k]) pb[k] = pairs[beg[k] + lane];
    }

    const int lane12 = lane * 12;

#pragma unroll
    for (int k = 0; k < 4; ++k) {
        const int p = 4 * wave + k;
        float a0 = 0.f, a1 = 0.f, a2 = 0.f, a3 = 0.f, a4 = 0.f, a5 = 0.f;
        const int c = cnt[k];
        unsigned int pbuf = pb[k];
        int done = 0;
        for (;;) {
            int m = min(c - done, 64);
            int j = 0;
            for (; j + 8 <= m; j += 8) {
                unsigned int w32[8];
                uint3 vv[8];
#pragma unroll
                for (int u = 0; u < 8; ++u)
                    w32[u] = __shfl(pbuf, j + u, 64);
#pragma unroll
                for (int u = 0; u < 8; ++u) {
                    int src = (int)(w32[u] & 0xFFFFu);
                    vv[u] = *(const uint3*)(xh + (size_t)src * 768 + lane12);
                }
#pragma unroll
                for (int u = 0; u < 8; ++u) {
                    float w = __half2float(__ushort_as_half((unsigned short)(w32[u] >> 16)));
                    float2 f0 = __half22float2(*(const __half2*)&vv[u].x);
                    float2 f1 = __half22float2(*(const __half2*)&vv[u].y);
                    float2 f2 = __half22float2(*(const __half2*)&vv[u].z);
                    a0 = fmaf(w, f0.x, a0); a1 = fmaf(w, f0.y, a1);
                    a2 = fmaf(w, f1.x, a2); a3 = fmaf(w, f1.y, a3);
                    a4 = fmaf(w, f2.x, a4); a5 = fmaf(w, f2.y, a5);
                }
            }
            for (; j < m; ++j) {
                unsigned int pw = __shfl(pbuf, j, 64);
                int src = (int)(pw & 0xFFFFu);
                uint3 vv = *(const uint3*)(xh + (size_t)src * 768 + lane12);
                float w = __half2float(__ushort_as_half((unsigned short)(pw >> 16)));
                float2 f0 = __half22float2(*(const __half2*)&vv.x);
                float2 f1 = __half22float2(*(const __half2*)&vv.y);
                float2 f2 = __half22float2(*(const __half2*)&vv.z);
                a0 = fmaf(w, f0.x, a0); a1 = fmaf(w, f0.y, a1);
                a2 = fmaf(w, f1.x, a2); a3 = fmaf(w, f1.y, a3);
                a4 = fmaf(w, f2.x, a4); a5 = fmaf(w, f2.y, a5);
            }
            done += m;
            if (done >= c) break;
            pbuf = 0;
            if (done + lane < c) pbuf = pairs[beg[k] + done + lane];   // rare (cnt>64)
        }
        float* aL = &aggL[p * CT + lane * 6];
        aL[0] = a0; aL[1] = a1; aL[2] = a2; aL[3] = a3; aL[4] = a4; aL[5] = a5;
    }
    __syncthreads();

    // ---- matmul: slots (g,q,t), 4 channels each; 576 slots over 384 threads ----
    const float* Ws[4] = { W0, W1, W2, W3 };
    for (int slot = tid; slot < GPB * 96; slot += 384) {
        int g = slot / 96;
        int rem = slot % 96;
        int q = rem / TT;       // 0..7
        int t = rem % TT;       // 0..11
        float acc[4];
#pragma unroll
        for (int i = 0; i < 4; ++i) acc[i] = bias[q * 4 + i];
#pragma unroll
        for (int b = 0; b < 4; ++b) {
            const float* __restrict__ Wb = Ws[b];
            const float* __restrict__ aL = &aggL[(g * 4 + b) * CT];
#pragma unroll
            for (int h = 0; h < 2; ++h) {
                float row[16];
#pragma unroll
                for (int kk = 0; kk < 16; ++kk) row[kk] = aL[(h * 16 + kk) * TT + t];
#pragma unroll
                for (int kk = 0; kk < 16; ++kk) {
#pragma unroll
                    for (int i = 0; i < 4; ++i)
                        acc[i] = fmaf(row[kk], Wb[(h * 16 + kk) * CC + q * 4 + i], acc[i]);
                }
            }
        }
#pragma unroll
        for (int i = 0; i < 4; ++i)
            out[(n0 + g) * CT + (q * 4 + i) * TT + t] = acc[i];
    }
}

// ---------------- launch ----------------

extern "C" void kernel_launch(void* const* d_in, const int* in_sizes, int n_in,
                              void* d_out, int out_size, void* d_ws, size_t ws_size,
                              hipStream_t stream) {
    const float* x    = (const float*)d_in[0];
    const float* bias = (const float*)d_in[13];
    const int*   ei[4] = { (const int*)d_in[1], (const int*)d_in[4],
                           (const int*)d_in[7], (const int*)d_in[10] };
    const float* ew[4] = { (const float*)d_in[2], (const float*)d_in[5],
                           (const float*)d_in[8], (const float*)d_in[11] };
    const float* W[4]  = { (const float*)d_in[3], (const float*)d_in[6],
                           (const float*)d_in[9], (const float*)d_in[12] };
    float* out = (float*)d_out;

    char* ws = (char*)d_ws;
    size_t OFF_PAIRS = 0;                                     // 4E u32 = 7.68 MB
    size_t OFF_XH    = OFF_PAIRS + (size_t)4 * NE * 4;        // N*CT2 half2 = 23.04 MB
    size_t OFF_CNT   = OFF_XH    + (size_t)NN * CT2 * 4;      // TOT int
    size_t OFF_OFFS  = OFF_CNT   + (size_t)TOT * 4;           // TOT+1 int
    size_t OFF_CUR   = OFF_OFFS  + (size_t)(TOT + 1) * 4;     // TOT int
    size_t OFF_PRE   = OFF_CUR   + (size_t)TOT * 4;           // TOT int
    size_t OFF_BSUM  = OFF_PRE   + (size_t)TOT * 4;           // 128 int
    size_t OFF_BBASE = OFF_BSUM  + (size_t)128 * 4;           // 128 int

    unsigned int* pairs = (unsigned int*)(ws + OFF_PAIRS);
    char*         xh    = ws + OFF_XH;
    int* cnt   = (int*)(ws + OFF_CNT);
    int* offs  = (int*)(ws + OFF_OFFS);
    int* cur   = (int*)(ws + OFF_CUR);
    int* pre   = (int*)(ws + OFF_PRE);
    int* bsum  = (int*)(ws + OFF_BSUM);
    int* bbase = (int*)(ws + OFF_BBASE);

    hipMemsetAsync(cnt, 0, (size_t)TOT * 4, stream);

    conv_kernel<<<(NN * CT2 + 255) / 256, 256, 0, stream>>>((const float2*)x, (__half2*)xh);

    dim3 eg((NE + 255) / 256, 4);
    hist_kernel<<<eg, 256, 0, stream>>>(ei[0], ei[1], ei[2], ei[3], cnt);
    scanA_kernel<<<NB, 1024, 0, stream>>>(cnt, pre, bsum);
    scanB_kernel<<<1, 128, 0, stream>>>(bsum, bbase, offs);
    scanC_kernel<<<NB, 1024, 0, stream>>>(pre, bbase, offs, cur);
    scatter_kernel<<<eg, 256, 0, stream>>>(ei[0], ei[1], ei[2], ei[3],
                                           ew[0], ew[1], ew[2], ew[3],
                                           cur, pairs);

    fused_kernel<<<NN / GPB, 384, 0, stream>>>(xh, pairs, offs,
                                               W[0], W[1], W[2], W[3],
                                               bias, out);
}